// Round 1
// 15941.623 us; speedup vs baseline: 1.6167x; 1.6167x over previous
//
#include <hip/hip_runtime.h>

#define EMB    1024
#define HID    2048
#define VOCAB  50257
#define T      256
#define NB_LOG 1024        // blocks in logits kernel (also # argmax partials)
#define NB_GAT (HID / 4)   // 512 blocks, 4 waves each, 1 hidden unit per wave
#define NB_CVT 2048

#define NEG_INF (-3.402823466e38f)

// ---------------------------------------------------------------------------
// ws layout (floats):
//   [0,       HID)    hA   (h buffer, even steps read this)
//   [HID,    2HID)    hB
//   [2HID,   3HID)    c
//   [3HID,   3HID+NB_LOG)            block_max (f32)
//   [3HID+NB_LOG, 3HID+2*NB_LOG)     block_idx (i32, stored as raw)
//   [8192 floats onward)             W_out converted to bf16 (ushort),
//                                    VOCAB*HID elements (~196 MiB)
// ---------------------------------------------------------------------------

__global__ void k_init(float* __restrict__ ws) {
    int i = blockIdx.x * blockDim.x + threadIdx.x;
    if (i < 3 * HID) ws[i] = 0.0f;   // hA, hB, c  <- zeros (ws is poisoned 0xAA)
}

__device__ __forceinline__ ushort f2bf(float f) {
    // round-to-nearest-even fp32 -> bf16 (weights are finite; no NaN handling)
    uint32_t u = __float_as_uint(f);
    u += 0x7FFFu + ((u >> 16) & 1u);
    return (ushort)(u >> 16);
}

// One-shot (per launch) conversion of W_out fp32 -> bf16 in workspace.
__global__ __launch_bounds__(256) void k_cvt(const float* __restrict__ src,
                                             ushort* __restrict__ dst, int n4) {
    const int stride = gridDim.x * blockDim.x;
    for (int i = blockIdx.x * blockDim.x + threadIdx.x; i < n4; i += stride) {
        float4 v = ((const float4*)src)[i];
        ushort4 o;
        o.x = f2bf(v.x); o.y = f2bf(v.y); o.z = f2bf(v.z); o.w = f2bf(v.w);
        ((ushort4*)dst)[i] = o;
    }
}

// One wave per hidden unit j. Computes the 4 gate rows (i,f,g,o), updates c,h.
// Full fp32: this is the error-amplifying recurrence path — keep it exact.
__global__ __launch_bounds__(256) void k_gates(
    const float* __restrict__ emb,
    const float* __restrict__ W_ih, const float* __restrict__ W_hh,
    const float* __restrict__ b_ih, const float* __restrict__ b_hh,
    const float* __restrict__ h_in, float* __restrict__ h_out,
    float* __restrict__ c,
    const float* __restrict__ bmax, const int* __restrict__ bidx,
    int step)
{
    __shared__ float xs[EMB];
    __shared__ float hs[HID];
    __shared__ float redv[4];
    __shared__ int   redi[4];
    __shared__ int   tok_s;

    const int tid  = threadIdx.x;
    const int wave = tid >> 6;
    const int lane = tid & 63;

    // ---- 1) determine tok (redundant per-block reduction of K2 partials) ----
    if (step == 0) {
        if (tid == 0) tok_s = 0;
    } else {
        float bv = NEG_INF; int bi = 0x7fffffff;
        for (int i = tid; i < NB_LOG; i += 256) {
            float v = bmax[i]; int ix = bidx[i];
            if (v > bv || (v == bv && ix < bi)) { bv = v; bi = ix; }
        }
        for (int off = 32; off; off >>= 1) {
            float ov = __shfl_down(bv, off);
            int   oi = __shfl_down(bi, off);
            if (ov > bv || (ov == bv && oi < bi)) { bv = ov; bi = oi; }
        }
        if (lane == 0) { redv[wave] = bv; redi[wave] = bi; }
        __syncthreads();
        if (tid == 0) {
            for (int w = 1; w < 4; ++w)
                if (redv[w] > bv || (redv[w] == bv && redi[w] < bi)) { bv = redv[w]; bi = redi[w]; }
            tok_s = bi;
        }
    }
    __syncthreads();
    const int tok = tok_s;

    // ---- 2) stage x = emb[tok] and h_in into LDS ----
    const float* xrow = emb + (size_t)tok * EMB;
    for (int i = tid; i < EMB; i += 256) xs[i] = xrow[i];
    for (int i = tid; i < HID; i += 256) hs[i] = h_in[i];
    __syncthreads();

    // ---- 3) one wave computes the 4 gate dot-products for unit j ----
    const int j = blockIdx.x * 4 + wave;   // NB_GAT*4 == HID exactly
    float gv[4];
    #pragma unroll
    for (int g = 0; g < 4; ++g) {
        const int row = g * HID + j;
        const float* wi = W_ih + (size_t)row * EMB;
        const float* wh = W_hh + (size_t)row * HID;
        float acc = 0.0f;
        #pragma unroll
        for (int k = lane * 4; k < EMB; k += 256) {
            float4 w4 = *(const float4*)(wi + k);
            float4 x4 = *(const float4*)(xs + k);
            acc += w4.x * x4.x + w4.y * x4.y + w4.z * x4.z + w4.w * x4.w;
        }
        #pragma unroll
        for (int k = lane * 4; k < HID; k += 256) {
            float4 w4 = *(const float4*)(wh + k);
            float4 h4 = *(const float4*)(hs + k);
            acc += w4.x * h4.x + w4.y * h4.y + w4.z * h4.z + w4.w * h4.w;
        }
        for (int off = 32; off; off >>= 1) acc += __shfl_down(acc, off);
        gv[g] = acc;   // meaningful on lane 0
    }

    // ---- 4) LSTM cell update (lane 0 of each wave owns unit j) ----
    if (lane == 0) {
        float gi = gv[0] + b_ih[j]           + b_hh[j];
        float gf = gv[1] + b_ih[HID + j]     + b_hh[HID + j];
        float gg = gv[2] + b_ih[2 * HID + j] + b_hh[2 * HID + j];
        float go = gv[3] + b_ih[3 * HID + j] + b_hh[3 * HID + j];
        float iv = 1.0f / (1.0f + expf(-gi));
        float fv = 1.0f / (1.0f + expf(-gf));
        float gvv = tanhf(gg);
        float ov = 1.0f / (1.0f + expf(-go));
        float cn = fv * c[j] + iv * gvv;
        c[j] = cn;
        h_out[j] = ov * tanhf(cn);
    }
}

// One wave per vocab row; bf16 W_out (halves the dominant HBM stream).
// h stays fp32 in LDS with the same conflict-free float4 access pattern.
__global__ __launch_bounds__(256) void k_logits_bf16(
    const ushort* __restrict__ Wb, const float* __restrict__ b_out,
    const float* __restrict__ h, float* __restrict__ out,
    float* __restrict__ bmax, int* __restrict__ bidx, int step)
{
    __shared__ float hs[HID];
    __shared__ float redv[4];
    __shared__ int   redi[4];

    const int tid  = threadIdx.x;
    const int wave = tid >> 6;
    const int lane = tid & 63;

    for (int i = tid; i < HID; i += 256) hs[i] = h[i];
    __syncthreads();

    float* orow = out + (size_t)step * VOCAB;
    float bv = NEG_INF; int bi = 0x7fffffff;

    for (int r = blockIdx.x * 4 + wave; r < VOCAB; r += NB_LOG * 4) {
        const ushort* w = Wb + (size_t)r * HID;
        float acc = 0.0f;
        #pragma unroll
        for (int k = lane * 4; k < HID; k += 256) {
            uint2 wv = *(const uint2*)(w + k);          // 4 bf16, 8 B/lane
            float4 h4 = *(const float4*)(hs + k);       // conflict-free (lane*16B)
            float w0 = __uint_as_float(wv.x << 16);
            float w1 = __uint_as_float(wv.x & 0xFFFF0000u);
            float w2 = __uint_as_float(wv.y << 16);
            float w3 = __uint_as_float(wv.y & 0xFFFF0000u);
            acc += w0 * h4.x + w1 * h4.y + w2 * h4.z + w3 * h4.w;
        }
        for (int off = 32; off; off >>= 1) acc += __shfl_down(acc, off);
        if (lane == 0) {
            float v = acc + b_out[r];
            orow[r] = v;
            if (v > bv) { bv = v; bi = r; }   // r strictly increasing per wave
        }
    }

    if (lane == 0) { redv[wave] = bv; redi[wave] = bi; }
    __syncthreads();
    if (tid == 0) {
        for (int w = 1; w < 4; ++w)
            if (redv[w] > bv || (redv[w] == bv && redi[w] < bi)) { bv = redv[w]; bi = redi[w]; }
        bmax[blockIdx.x] = bv;
        bidx[blockIdx.x] = bi;
    }
}

// fp32 fallback (used only if workspace is too small for bf16 W_out copy)
__global__ __launch_bounds__(256) void k_logits(
    const float* __restrict__ W_out, const float* __restrict__ b_out,
    const float* __restrict__ h, float* __restrict__ out,
    float* __restrict__ bmax, int* __restrict__ bidx, int step)
{
    __shared__ float hs[HID];
    __shared__ float redv[4];
    __shared__ int   redi[4];

    const int tid  = threadIdx.x;
    const int wave = tid >> 6;
    const int lane = tid & 63;

    for (int i = tid; i < HID; i += 256) hs[i] = h[i];
    __syncthreads();

    float* orow = out + (size_t)step * VOCAB;
    float bv = NEG_INF; int bi = 0x7fffffff;

    for (int r = blockIdx.x * 4 + wave; r < VOCAB; r += NB_LOG * 4) {
        const float* w = W_out + (size_t)r * HID;
        float acc = 0.0f;
        #pragma unroll
        for (int k = lane * 4; k < HID; k += 256) {
            float4 w4 = *(const float4*)(w + k);
            float4 h4 = *(const float4*)(hs + k);
            acc += w4.x * h4.x + w4.y * h4.y + w4.z * h4.z + w4.w * h4.w;
        }
        for (int off = 32; off; off >>= 1) acc += __shfl_down(acc, off);
        if (lane == 0) {
            float v = acc + b_out[r];
            orow[r] = v;
            if (v > bv) { bv = v; bi = r; }
        }
    }

    if (lane == 0) { redv[wave] = bv; redi[wave] = bi; }
    __syncthreads();
    if (tid == 0) {
        for (int w = 1; w < 4; ++w)
            if (redv[w] > bv || (redv[w] == bv && redi[w] < bi)) { bv = redv[w]; bi = redi[w]; }
        bmax[blockIdx.x] = bv;
        bidx[blockIdx.x] = bi;
    }
}

extern "C" void kernel_launch(void* const* d_in, const int* in_sizes, int n_in,
                              void* d_out, int out_size, void* d_ws, size_t ws_size,
                              hipStream_t stream) {
    const float* emb   = (const float*)d_in[0];
    const float* W_ih  = (const float*)d_in[1];
    const float* W_hh  = (const float*)d_in[2];
    const float* b_ih  = (const float*)d_in[3];
    const float* b_hh  = (const float*)d_in[4];
    const float* W_out = (const float*)d_in[5];
    const float* b_out = (const float*)d_in[6];
    float* out = (float*)d_out;

    float* ws   = (float*)d_ws;
    float* hA   = ws;                 // step-even input h
    float* hB   = ws + HID;
    float* c    = ws + 2 * HID;
    float* bmax = ws + 3 * HID;
    int*   bidx = (int*)(ws + 3 * HID + NB_LOG);
    ushort* Wb  = (ushort*)(ws + 8192);   // bf16 W_out copy (32 KiB offset, 16B-aligned)

    const size_t n_wout  = (size_t)VOCAB * HID;
    const size_t ws_need = 8192 * sizeof(float) + n_wout * sizeof(ushort);
    const bool use_bf16  = (ws_size >= ws_need);

    k_init<<<(3 * HID + 255) / 256, 256, 0, stream>>>(ws);
    if (use_bf16) {
        k_cvt<<<NB_CVT, 256, 0, stream>>>(W_out, Wb, (int)(n_wout / 4));
    }

    for (int t = 0; t < T; ++t) {
        float* h_in  = (t & 1) ? hB : hA;
        float* h_out = (t & 1) ? hA : hB;
        k_gates<<<NB_GAT, 256, 0, stream>>>(emb, W_ih, W_hh, b_ih, b_hh,
                                            h_in, h_out, c, bmax, bidx, t);
        if (use_bf16) {
            k_logits_bf16<<<NB_LOG, 256, 0, stream>>>(Wb, b_out, h_out, out, bmax, bidx, t);
        } else {
            k_logits<<<NB_LOG, 256, 0, stream>>>(W_out, b_out, h_out, out, bmax, bidx, t);
        }
    }
}

// Round 2
// 14539.581 us; speedup vs baseline: 1.7726x; 1.0964x over previous
//
#include <hip/hip_runtime.h>

#define EMB    1024
#define HID    2048
#define VOCAB  50257
#define T      256
#define NB_LOG 2048        // blocks in logits kernel (also # argmax partials)
#define NB_GAT 2048        // gates: one block per hidden unit, 4 waves = 4 gates
#define NB_CVT 2048

#define NEG_INF (-3.402823466e38f)

// ---------------------------------------------------------------------------
// ws layout (floats):
//   [0,       HID)    hA   (h buffer, even steps read this)
//   [HID,    2HID)    hB
//   [2HID,   3HID)    c
//   [3HID,        3HID+NB_LOG)      block_max (f32)      [6144, 8192)
//   [3HID+NB_LOG, 3HID+2*NB_LOG)    block_idx (i32 raw)  [8192, 10240)
//   [16384 onward)                  bf16 weight copies:
//       Wb_out : VOCAB*HID ushorts (~196 MiB)
//       Wb_ih  : 4*HID*EMB ushorts (~16 MiB)
//       Wb_hh  : 4*HID*HID ushorts (~32 MiB)
// ---------------------------------------------------------------------------

__global__ void k_init(float* __restrict__ ws) {
    int i = blockIdx.x * blockDim.x + threadIdx.x;
    if (i < 3 * HID) ws[i] = 0.0f;   // hA, hB, c  <- zeros (ws is poisoned 0xAA)
}

__device__ __forceinline__ ushort f2bf(float f) {
    // round-to-nearest-even fp32 -> bf16 (weights are finite; no NaN handling)
    uint32_t u = __float_as_uint(f);
    u += 0x7FFFu + ((u >> 16) & 1u);
    return (ushort)(u >> 16);
}

__global__ __launch_bounds__(256) void k_cvt(const float* __restrict__ src,
                                             ushort* __restrict__ dst, int n4) {
    const int stride = gridDim.x * blockDim.x;
    for (int i = blockIdx.x * blockDim.x + threadIdx.x; i < n4; i += stride) {
        float4 v = ((const float4*)src)[i];
        ushort4 o;
        o.x = f2bf(v.x); o.y = f2bf(v.y); o.z = f2bf(v.z); o.w = f2bf(v.w);
        ((ushort4*)dst)[i] = o;
    }
}

// ---------------------------------------------------------------------------
// tok reduction helper: redundant per-block reduction of the NB_LOG partials.
// Returns the argmax token (valid in all threads after the call).
// ---------------------------------------------------------------------------
__device__ __forceinline__ int resolve_tok(
    const float* __restrict__ bmax, const int* __restrict__ bidx,
    int step, int tid, int wave, int lane,
    float* redv, int* redi, int* tok_s)
{
    if (step == 0) {
        if (tid == 0) *tok_s = 0;
    } else {
        float bv = NEG_INF; int bi = 0x7fffffff;
        for (int i = tid; i < NB_LOG; i += 256) {
            float v = bmax[i]; int ix = bidx[i];
            if (v > bv || (v == bv && ix < bi)) { bv = v; bi = ix; }
        }
        for (int off = 32; off; off >>= 1) {
            float ov = __shfl_down(bv, off);
            int   oi = __shfl_down(bi, off);
            if (ov > bv || (ov == bv && oi < bi)) { bv = ov; bi = oi; }
        }
        if (lane == 0) { redv[wave] = bv; redi[wave] = bi; }
        __syncthreads();
        if (tid == 0) {
            for (int w = 1; w < 4; ++w)
                if (redv[w] > bv || (redv[w] == bv && redi[w] < bi)) { bv = redv[w]; bi = redi[w]; }
            *tok_s = bi;
        }
    }
    __syncthreads();
    return *tok_s;
}

// ---------------------------------------------------------------------------
// Gates, bf16 weights. One block per hidden unit j (2048 blocks -> 8 blk/CU,
// 32 waves/CU). Wave g computes gate-row g*HID+j; LDS combine; thread 0 does
// the cell update. Accumulation fp32.
// ---------------------------------------------------------------------------
__global__ __launch_bounds__(256) void k_gates_bf16(
    const float* __restrict__ emb,
    const ushort* __restrict__ Wi, const ushort* __restrict__ Wh,
    const float* __restrict__ b_ih, const float* __restrict__ b_hh,
    const float* __restrict__ h_in, float* __restrict__ h_out,
    float* __restrict__ c,
    const float* __restrict__ bmax, const int* __restrict__ bidx,
    int step)
{
    __shared__ float xs[EMB];
    __shared__ float hs[HID];
    __shared__ float gvs[4];
    __shared__ float redv[4];
    __shared__ int   redi[4];
    __shared__ int   tok_s;

    const int tid  = threadIdx.x;
    const int wave = tid >> 6;
    const int lane = tid & 63;

    const int tok = resolve_tok(bmax, bidx, step, tid, wave, lane, redv, redi, &tok_s);

    const float* xrow = emb + (size_t)tok * EMB;
    for (int i = tid; i < EMB; i += 256) xs[i] = xrow[i];
    for (int i = tid; i < HID; i += 256) hs[i] = h_in[i];
    __syncthreads();

    const int j   = blockIdx.x;
    const int row = wave * HID + j;          // gate `wave` (i,f,g,o), unit j
    const ushort* wi = Wi + (size_t)row * EMB;
    const ushort* wh = Wh + (size_t)row * HID;

    float acc = 0.0f;
    #pragma unroll
    for (int k = lane * 8; k < EMB; k += 512) {       // 2 iters, 16 B/lane
        uint4  wv = *(const uint4*)(wi + k);
        float4 a  = *(const float4*)(xs + k);
        float4 b  = *(const float4*)(xs + k + 4);
        acc += __uint_as_float(wv.x << 16)          * a.x;
        acc += __uint_as_float(wv.x & 0xFFFF0000u)  * a.y;
        acc += __uint_as_float(wv.y << 16)          * a.z;
        acc += __uint_as_float(wv.y & 0xFFFF0000u)  * a.w;
        acc += __uint_as_float(wv.z << 16)          * b.x;
        acc += __uint_as_float(wv.z & 0xFFFF0000u)  * b.y;
        acc += __uint_as_float(wv.w << 16)          * b.z;
        acc += __uint_as_float(wv.w & 0xFFFF0000u)  * b.w;
    }
    #pragma unroll
    for (int k = lane * 8; k < HID; k += 512) {       // 4 iters, 16 B/lane
        uint4  wv = *(const uint4*)(wh + k);
        float4 a  = *(const float4*)(hs + k);
        float4 b  = *(const float4*)(hs + k + 4);
        acc += __uint_as_float(wv.x << 16)          * a.x;
        acc += __uint_as_float(wv.x & 0xFFFF0000u)  * a.y;
        acc += __uint_as_float(wv.y << 16)          * a.z;
        acc += __uint_as_float(wv.y & 0xFFFF0000u)  * a.w;
        acc += __uint_as_float(wv.z << 16)          * b.x;
        acc += __uint_as_float(wv.z & 0xFFFF0000u)  * b.y;
        acc += __uint_as_float(wv.w << 16)          * b.z;
        acc += __uint_as_float(wv.w & 0xFFFF0000u)  * b.w;
    }
    for (int off = 32; off; off >>= 1) acc += __shfl_down(acc, off);
    if (lane == 0) gvs[wave] = acc;
    __syncthreads();

    if (tid == 0) {
        float gi = gvs[0] + b_ih[j]           + b_hh[j];
        float gf = gvs[1] + b_ih[HID + j]     + b_hh[HID + j];
        float gg = gvs[2] + b_ih[2 * HID + j] + b_hh[2 * HID + j];
        float go = gvs[3] + b_ih[3 * HID + j] + b_hh[3 * HID + j];
        float iv = 1.0f / (1.0f + expf(-gi));
        float fv = 1.0f / (1.0f + expf(-gf));
        float gvv = tanhf(gg);
        float ov = 1.0f / (1.0f + expf(-go));
        float cn = fv * c[j] + iv * gvv;
        c[j] = cn;
        h_out[j] = ov * tanhf(cn);
    }
}

// fp32 gates fallback (restructured to 2048 blocks as well)
__global__ __launch_bounds__(256) void k_gates_f32(
    const float* __restrict__ emb,
    const float* __restrict__ W_ih, const float* __restrict__ W_hh,
    const float* __restrict__ b_ih, const float* __restrict__ b_hh,
    const float* __restrict__ h_in, float* __restrict__ h_out,
    float* __restrict__ c,
    const float* __restrict__ bmax, const int* __restrict__ bidx,
    int step)
{
    __shared__ float xs[EMB];
    __shared__ float hs[HID];
    __shared__ float gvs[4];
    __shared__ float redv[4];
    __shared__ int   redi[4];
    __shared__ int   tok_s;

    const int tid  = threadIdx.x;
    const int wave = tid >> 6;
    const int lane = tid & 63;

    const int tok = resolve_tok(bmax, bidx, step, tid, wave, lane, redv, redi, &tok_s);

    const float* xrow = emb + (size_t)tok * EMB;
    for (int i = tid; i < EMB; i += 256) xs[i] = xrow[i];
    for (int i = tid; i < HID; i += 256) hs[i] = h_in[i];
    __syncthreads();

    const int j   = blockIdx.x;
    const int row = wave * HID + j;
    const float* wi = W_ih + (size_t)row * EMB;
    const float* wh = W_hh + (size_t)row * HID;

    float acc = 0.0f;
    #pragma unroll
    for (int k = lane * 4; k < EMB; k += 256) {
        float4 w4 = *(const float4*)(wi + k);
        float4 x4 = *(const float4*)(xs + k);
        acc += w4.x * x4.x + w4.y * x4.y + w4.z * x4.z + w4.w * x4.w;
    }
    #pragma unroll
    for (int k = lane * 4; k < HID; k += 256) {
        float4 w4 = *(const float4*)(wh + k);
        float4 h4 = *(const float4*)(hs + k);
        acc += w4.x * h4.x + w4.y * h4.y + w4.z * h4.z + w4.w * h4.w;
    }
    for (int off = 32; off; off >>= 1) acc += __shfl_down(acc, off);
    if (lane == 0) gvs[wave] = acc;
    __syncthreads();

    if (tid == 0) {
        float gi = gvs[0] + b_ih[j]           + b_hh[j];
        float gf = gvs[1] + b_ih[HID + j]     + b_hh[HID + j];
        float gg = gvs[2] + b_ih[2 * HID + j] + b_hh[2 * HID + j];
        float go = gvs[3] + b_ih[3 * HID + j] + b_hh[3 * HID + j];
        float iv = 1.0f / (1.0f + expf(-gi));
        float fv = 1.0f / (1.0f + expf(-gf));
        float gvv = tanhf(gg);
        float ov = 1.0f / (1.0f + expf(-go));
        float cn = fv * c[j] + iv * gvv;
        c[j] = cn;
        h_out[j] = ov * tanhf(cn);
    }
}

// ---------------------------------------------------------------------------
// Logits, bf16 W_out. 2048 blocks (8 blk/CU, 32 waves/CU), one wave per row,
// ~6 rows per wave. 16 B/lane weight loads.
// ---------------------------------------------------------------------------
__global__ __launch_bounds__(256) void k_logits_bf16(
    const ushort* __restrict__ Wb, const float* __restrict__ b_out,
    const float* __restrict__ h, float* __restrict__ out,
    float* __restrict__ bmax, int* __restrict__ bidx, int step)
{
    __shared__ float hs[HID];
    __shared__ float redv[4];
    __shared__ int   redi[4];

    const int tid  = threadIdx.x;
    const int wave = tid >> 6;
    const int lane = tid & 63;

    for (int i = tid; i < HID; i += 256) hs[i] = h[i];
    __syncthreads();

    float* orow = out + (size_t)step * VOCAB;
    float bv = NEG_INF; int bi = 0x7fffffff;

    for (int r = blockIdx.x * 4 + wave; r < VOCAB; r += NB_LOG * 4) {
        const ushort* w = Wb + (size_t)r * HID;
        float acc = 0.0f;
        #pragma unroll
        for (int k = lane * 8; k < HID; k += 512) {   // 4 iters, 16 B/lane
            uint4  wv = *(const uint4*)(w + k);
            float4 a  = *(const float4*)(hs + k);
            float4 b  = *(const float4*)(hs + k + 4);
            acc += __uint_as_float(wv.x << 16)          * a.x;
            acc += __uint_as_float(wv.x & 0xFFFF0000u)  * a.y;
            acc += __uint_as_float(wv.y << 16)          * a.z;
            acc += __uint_as_float(wv.y & 0xFFFF0000u)  * a.w;
            acc += __uint_as_float(wv.z << 16)          * b.x;
            acc += __uint_as_float(wv.z & 0xFFFF0000u)  * b.y;
            acc += __uint_as_float(wv.w << 16)          * b.z;
            acc += __uint_as_float(wv.w & 0xFFFF0000u)  * b.w;
        }
        for (int off = 32; off; off >>= 1) acc += __shfl_down(acc, off);
        if (lane == 0) {
            float v = acc + b_out[r];
            orow[r] = v;
            if (v > bv) { bv = v; bi = r; }   // r strictly increasing per wave
        }
    }

    if (lane == 0) { redv[wave] = bv; redi[wave] = bi; }
    __syncthreads();
    if (tid == 0) {
        for (int w = 1; w < 4; ++w)
            if (redv[w] > bv || (redv[w] == bv && redi[w] < bi)) { bv = redv[w]; bi = redi[w]; }
        bmax[blockIdx.x] = bv;
        bidx[blockIdx.x] = bi;
    }
}

// fp32 logits fallback (only if workspace can't even hold bf16 W_out)
__global__ __launch_bounds__(256) void k_logits_f32(
    const float* __restrict__ W_out, const float* __restrict__ b_out,
    const float* __restrict__ h, float* __restrict__ out,
    float* __restrict__ bmax, int* __restrict__ bidx, int step)
{
    __shared__ float hs[HID];
    __shared__ float redv[4];
    __shared__ int   redi[4];

    const int tid  = threadIdx.x;
    const int wave = tid >> 6;
    const int lane = tid & 63;

    for (int i = tid; i < HID; i += 256) hs[i] = h[i];
    __syncthreads();

    float* orow = out + (size_t)step * VOCAB;
    float bv = NEG_INF; int bi = 0x7fffffff;

    for (int r = blockIdx.x * 4 + wave; r < VOCAB; r += NB_LOG * 4) {
        const float* w = W_out + (size_t)r * HID;
        float acc = 0.0f;
        #pragma unroll
        for (int k = lane * 4; k < HID; k += 256) {
            float4 w4 = *(const float4*)(w + k);
            float4 h4 = *(const float4*)(hs + k);
            acc += w4.x * h4.x + w4.y * h4.y + w4.z * h4.z + w4.w * h4.w;
        }
        for (int off = 32; off; off >>= 1) acc += __shfl_down(acc, off);
        if (lane == 0) {
            float v = acc + b_out[r];
            orow[r] = v;
            if (v > bv) { bv = v; bi = r; }
        }
    }

    if (lane == 0) { redv[wave] = bv; redi[wave] = bi; }
    __syncthreads();
    if (tid == 0) {
        for (int w = 1; w < 4; ++w)
            if (redv[w] > bv || (redv[w] == bv && redi[w] < bi)) { bv = redv[w]; bi = redi[w]; }
        bmax[blockIdx.x] = bv;
        bidx[blockIdx.x] = bi;
    }
}

extern "C" void kernel_launch(void* const* d_in, const int* in_sizes, int n_in,
                              void* d_out, int out_size, void* d_ws, size_t ws_size,
                              hipStream_t stream) {
    const float* emb   = (const float*)d_in[0];
    const float* W_ih  = (const float*)d_in[1];
    const float* W_hh  = (const float*)d_in[2];
    const float* b_ih  = (const float*)d_in[3];
    const float* b_hh  = (const float*)d_in[4];
    const float* W_out = (const float*)d_in[5];
    const float* b_out = (const float*)d_in[6];
    float* out = (float*)d_out;

    float* ws   = (float*)d_ws;
    float* hA   = ws;
    float* hB   = ws + HID;
    float* c    = ws + 2 * HID;
    float* bmax = ws + 3 * HID;
    int*   bidx = (int*)(ws + 3 * HID + NB_LOG);

    const size_t n_wout = (size_t)VOCAB * HID;      // 102,926,336
    const size_t n_wih  = (size_t)4 * HID * EMB;    //   8,388,608
    const size_t n_whh  = (size_t)4 * HID * HID;    //  16,777,216

    const size_t f_wout = 16384;                    // float offsets
    const size_t f_wih  = f_wout + n_wout / 2;
    const size_t f_whh  = f_wih  + n_wih  / 2;
    const size_t f_end  = f_whh  + n_whh  / 2;

    const size_t need_part = f_wih * sizeof(float); // W_out only (~206 MB, proven)
    const size_t need_full = f_end * sizeof(float); // all three  (~256 MB)

    ushort* Wb_out = (ushort*)(ws + f_wout);
    ushort* Wb_ih  = (ushort*)(ws + f_wih);
    ushort* Wb_hh  = (ushort*)(ws + f_whh);

    const int tier = (ws_size >= need_full) ? 2 : (ws_size >= need_part) ? 1 : 0;

    k_init<<<(3 * HID + 255) / 256, 256, 0, stream>>>(ws);
    if (tier >= 1)
        k_cvt<<<NB_CVT, 256, 0, stream>>>(W_out, Wb_out, (int)(n_wout / 4));
    if (tier == 2) {
        k_cvt<<<NB_CVT, 256, 0, stream>>>(W_ih, Wb_ih, (int)(n_wih / 4));
        k_cvt<<<NB_CVT, 256, 0, stream>>>(W_hh, Wb_hh, (int)(n_whh / 4));
    }

    for (int t = 0; t < T; ++t) {
        float* h_in  = (t & 1) ? hB : hA;
        float* h_out = (t & 1) ? hA : hB;
        if (tier == 2) {
            k_gates_bf16<<<NB_GAT, 256, 0, stream>>>(emb, Wb_ih, Wb_hh, b_ih, b_hh,
                                                     h_in, h_out, c, bmax, bidx, t);
        } else {
            k_gates_f32<<<NB_GAT, 256, 0, stream>>>(emb, W_ih, W_hh, b_ih, b_hh,
                                                    h_in, h_out, c, bmax, bidx, t);
        }
        if (tier >= 1) {
            k_logits_bf16<<<NB_LOG, 256, 0, stream>>>(Wb_out, b_out, h_out, out, bmax, bidx, t);
        } else {
            k_logits_f32<<<NB_LOG, 256, 0, stream>>>(W_out, b_out, h_out, out, bmax, bidx, t);
        }
    }
}